// Round 3
// baseline (220.943 us; speedup 1.0000x reference)
//
#include <hip/hip_runtime.h>

// Weighted BCE over (N=4, C=3, 128^3) fp32.
// Identity (t in {0,1} exactly): t*log(p)+(1-t)*log(1-p) = log(t ? p : 1-p),
// and count(t!=0) = sum(t) (float-exact below 2^24).
// R2 post-mortem: latency-bound (VALUBusy 16%, HBM 16%) -> this version
// batches 8 independent dwordx4 loads per loop body to raise bytes-in-flight.

#define THREADS 256
#define BLOCKS_PER_SLAB 128
#define NSLABS 12   // N*C = 4*3
#define NCHAN 3

__device__ __forceinline__ void acc4(float4 p, float4 t, float& lsum, float& lcnt)
{
    float pp[4] = {p.x, p.y, p.z, p.w};
    float tt[4] = {t.x, t.y, t.z, t.w};
#pragma unroll
    for (int k = 0; k < 4; ++k) {
        bool  pos = (tt[k] != 0.0f);
        float x   = pos ? pp[k] : (1.0f - pp[k]);   // cmp + sub + cndmask
        lsum += fmaxf(__logf(x), -100.0f);          // one v_log_f32
        lcnt += tt[k];                               // exact count (t in {0,1})
    }
}

__global__ __launch_bounds__(THREADS) void bce_partial(
    const float* __restrict__ input,
    const float* __restrict__ target,
    float* __restrict__ bce_sum,    // [3]
    float* __restrict__ ones_cnt,   // [3]
    int S4)                          // float4 elements per slab (524288)
{
    const int slab = blockIdx.x / BLOCKS_PER_SLAB;
    const int blk  = blockIdx.x % BLOCKS_PER_SLAB;
    const int c    = slab % NCHAN;  // block-uniform

    const float4* __restrict__ in4 = (const float4*)input  + (size_t)slab * S4;
    const float4* __restrict__ tg4 = (const float4*)target + (size_t)slab * S4;

    float lsum = 0.0f;
    float lcnt = 0.0f;

    const int stride = BLOCKS_PER_SLAB * THREADS;   // 32768 float4
    int i = blk * THREADS + (int)threadIdx.x;

    // Batched: issue 8 independent 16B loads, then compute 16 elements.
    for (; i + 3 * stride < S4; i += 4 * stride) {
        float4 p0 = in4[i];
        float4 p1 = in4[i +     stride];
        float4 p2 = in4[i + 2 * stride];
        float4 p3 = in4[i + 3 * stride];
        float4 t0 = tg4[i];
        float4 t1 = tg4[i +     stride];
        float4 t2 = tg4[i + 2 * stride];
        float4 t3 = tg4[i + 3 * stride];
        acc4(p0, t0, lsum, lcnt);
        acc4(p1, t1, lsum, lcnt);
        acc4(p2, t2, lsum, lcnt);
        acc4(p3, t3, lsum, lcnt);
    }
    for (; i < S4; i += stride)                     // remainder (none for 524288)
        acc4(in4[i], tg4[i], lsum, lcnt);

    // wave (64-lane) reduction
#pragma unroll
    for (int off = 32; off > 0; off >>= 1) {
        lsum += __shfl_down(lsum, off, 64);
        lcnt += __shfl_down(lcnt, off, 64);
    }

    __shared__ float wsum[THREADS / 64];
    __shared__ float wcnt[THREADS / 64];
    const int lane = threadIdx.x & 63;
    const int wave = threadIdx.x >> 6;
    if (lane == 0) { wsum[wave] = lsum; wcnt[wave] = lcnt; }
    __syncthreads();
    if (threadIdx.x == 0) {
        float s = 0.0f, n = 0.0f;
#pragma unroll
        for (int w = 0; w < THREADS / 64; ++w) { s += wsum[w]; n += wcnt[w]; }
        atomicAdd(&bce_sum[c], s);
        atomicAdd(&ones_cnt[c], n);
    }
}

__global__ void bce_final(const float* __restrict__ bce_sum,
                          const float* __restrict__ ones_cnt,
                          float* __restrict__ out,
                          float per_chan_total)
{
    if (threadIdx.x == 0 && blockIdx.x == 0) {
        float acc = 0.0f;
#pragma unroll
        for (int c = 0; c < NCHAN; ++c) {
            float ones = ones_cnt[c];
            float w    = (ones > 0.0f) ? (per_chan_total / fmaxf(ones, 1.0f)) : 1000.0f;
            float bce  = -(bce_sum[c] / per_chan_total);
            acc += w * bce;
        }
        out[0] = acc / (float)NCHAN;
    }
}

extern "C" void kernel_launch(void* const* d_in, const int* in_sizes, int n_in,
                              void* d_out, int out_size, void* d_ws, size_t ws_size,
                              hipStream_t stream)
{
    const float* input  = (const float*)d_in[0];
    const float* target = (const float*)d_in[1];
    float*       out    = (float*)d_out;

    float* bce_sum  = (float*)d_ws;
    float* ones_cnt = (float*)((char*)d_ws + NCHAN * sizeof(float));

    hipMemsetAsync(d_ws, 0, 2 * NCHAN * sizeof(float), stream);

    const long long total = (long long)in_sizes[0];        // 25,165,824
    const int       S4    = (int)(total / (NSLABS * 4));    // 524,288
    const float     M     = (float)(total / NCHAN);         // 8,388,608

    bce_partial<<<NSLABS * BLOCKS_PER_SLAB, THREADS, 0, stream>>>(
        input, target, bce_sum, ones_cnt, S4);
    bce_final<<<1, 64, 0, stream>>>(bce_sum, ones_cnt, out, M);
}